// Round 1
// baseline (2999.397 us; speedup 1.0000x reference)
//
#include <hip/hip_runtime.h>
#include <hip/hip_bf16.h>
#include <stdint.h>

// SpikingSelfAttention: out = (q*cumsum_t(k*v)) @ Wp^T + bp, q/k/v = LIF(x@W^T)
// T=4, B=16, N=1024, D=512 -> M = B*N = 16384 flattened rows.
//
// Numerics: spike = (mem >= 1.0) hard threshold; ~1e8 decisions with membrane
// density ~0.22 near threshold. Reference check is vs an fp64 golden ref, so
// all pre-spike arithmetic (qkv GEMMs + LIF recurrence) is done with fp64
// accumulation (band vs fp64 ref ~1e-13 -> ~zero spike flips). Post-spike
// values are exact small ints (s = q*context in {0..4}, exact in bf16); the
// final GEMM only needs ~1e-3 abs accuracy -> fp32 FMA is plenty.

#define T_ 4
#define B_ 16
#define N_ 1024
#define M_ (B_ * N_)   // 16384
#define D_ 512

struct __align__(8) US4 { unsigned short x, y, z, w; };

static __device__ __forceinline__ float bf16_to_f32(unsigned short u) {
  union { uint32_t i; float f; } c; c.i = ((uint32_t)u) << 16; return c.f;
}
static __device__ __forceinline__ unsigned short f32_to_bf16_exact(float f) {
  union { float f; uint32_t i; } c; c.f = f; return (unsigned short)(c.i >> 16);
}

// ---------------------------------------------------------------------------
// Kernel 1: fused qkv GEMM (fp64 accum) + LIF + context cumsum + s store.
// Block: 256 threads = (tx 0..63 -> d, ty 0..3 -> m-group of 4).
// Tile: 16 m-rows x 64 d-cols, all T=4 timesteps and all 3 matrices at once,
// so the LIF recurrence (sequential in t) runs entirely in registers.
// ---------------------------------------------------------------------------
__global__ __launch_bounds__(256, 2)
void qkv_lif_kernel(const float* __restrict__ x,    // (T, M, D)
                    const float* __restrict__ Wq,   // (D, D) row-major [d][k]
                    const float* __restrict__ Wk,
                    const float* __restrict__ Wv,
                    unsigned short* __restrict__ s_out) {  // (T, M, D) bf16
  __shared__ __align__(16) float Xs[T_][16][32];   // X tiles, all 4 timesteps
  __shared__ float Ws[3][64][33];                  // W tiles, +1 pad (bank)
  const int tid = threadIdx.x;
  const int tx = tid & 63;   // d within tile
  const int ty = tid >> 6;   // m group
  const int m0 = blockIdx.x * 16;
  const int d0 = blockIdx.y * 64;

  double acc[T_][3][4];
  #pragma unroll
  for (int t = 0; t < T_; ++t)
    #pragma unroll
    for (int mat = 0; mat < 3; ++mat)
      #pragma unroll
      for (int i = 0; i < 4; ++i) acc[t][mat][i] = 0.0;

  for (int k0 = 0; k0 < D_; k0 += 32) {
    __syncthreads();
    // Stage X: 4t x 16m x 32k floats = 512 float4, 2 per thread (coalesced).
    #pragma unroll
    for (int c = 0; c < 2; ++c) {
      int idx = c * 256 + tid;          // 0..511
      int k4 = idx & 7, row = idx >> 3; // row 0..63
      int t = row >> 4, m = row & 15;
      float4 v = *reinterpret_cast<const float4*>(
          x + ((size_t)t * M_ + (size_t)(m0 + m)) * D_ + k0 + k4 * 4);
      *reinterpret_cast<float4*>(&Xs[t][m][k4 * 4]) = v;
    }
    // Stage W (q,k,v): 3 x 64d x 32k = 1536 float4, 6 per thread.
    #pragma unroll
    for (int c = 0; c < 6; ++c) {
      int idx = c * 256 + tid;          // 0..1535
      int k4 = idx & 7, row = idx >> 3; // row 0..191
      int mat = row >> 6, dd = row & 63;
      const float* wp = (mat == 0) ? Wq : ((mat == 1) ? Wk : Wv);
      float4 v = *reinterpret_cast<const float4*>(
          wp + (size_t)(d0 + dd) * D_ + k0 + k4 * 4);
      Ws[mat][dd][k4 * 4 + 0] = v.x;
      Ws[mat][dd][k4 * 4 + 1] = v.y;
      Ws[mat][dd][k4 * 4 + 2] = v.z;
      Ws[mat][dd][k4 * 4 + 3] = v.w;
    }
    __syncthreads();
    // Inner product: 48 v_fma_f64 per kk per thread.
    #pragma unroll 8
    for (int kk = 0; kk < 32; ++kk) {
      double wq = (double)Ws[0][tx][kk];
      double wk = (double)Ws[1][tx][kk];
      double wv = (double)Ws[2][tx][kk];
      #pragma unroll
      for (int t = 0; t < T_; ++t) {
        #pragma unroll
        for (int i = 0; i < 4; ++i) {
          double xv = (double)Xs[t][ty * 4 + i][kk];  // wave-broadcast read
          acc[t][0][i] = fma(xv, wq, acc[t][0][i]);
          acc[t][1][i] = fma(xv, wk, acc[t][1][i]);
          acc[t][2][i] = fma(xv, wv, acc[t][2][i]);
        }
      }
    }
  }

  // LIF over t (fp64, matches fp64 golden ref), then kv/context/s.
  #pragma unroll
  for (int i = 0; i < 4; ++i) {
    double mq = 0.0, mk = 0.0, mv = 0.0;
    int ctx = 0;
    const size_t base = (size_t)(m0 + ty * 4 + i) * D_ + d0 + tx;
    #pragma unroll
    for (int t = 0; t < T_; ++t) {
      mq = mq * 0.9 + acc[t][0][i];
      mk = mk * 0.9 + acc[t][1][i];
      mv = mv * 0.9 + acc[t][2][i];
      int sq = (mq >= 1.0) ? 1 : 0; mq -= (double)sq;   // soft reset, THR=1
      int sk = (mk >= 1.0) ? 1 : 0; mk -= (double)sk;
      int sv = (mv >= 1.0) ? 1 : 0; mv -= (double)sv;
      ctx += sk & sv;                       // context = cumsum_t(k*v)
      int sval = sq ? ctx : 0;              // s = q * context, in {0..4}
      s_out[(size_t)t * (M_ * D_) + base] = f32_to_bf16_exact((float)sval);
    }
  }
}

// ---------------------------------------------------------------------------
// Kernel 2: out = s @ Wp^T + bp   (R = T*M = 65536 rows, 512 cols, K = 512)
// fp32 vector FMA; s is exact in bf16, so only accumulation rounding (~1e-6).
// Block 256 = (txj 0..15 -> j-group, tyr 0..15 -> r-group), 64x64 tile.
// ---------------------------------------------------------------------------
__global__ __launch_bounds__(256, 2)
void out_gemm_kernel(const unsigned short* __restrict__ s,  // (R, D) bf16
                     const float* __restrict__ Wp,          // (D, D) [j][d]
                     const float* __restrict__ bp,          // (D,)
                     float* __restrict__ out) {             // (R, D)
  __shared__ float As[64][33];
  __shared__ float Bs[64][33];
  const int tid = threadIdx.x;
  const int txj = tid & 15;
  const int tyr = tid >> 4;
  const int r0 = blockIdx.x * 64;
  const int j0 = blockIdx.y * 64;

  float acc[4][4];
  #pragma unroll
  for (int i = 0; i < 4; ++i)
    #pragma unroll
    for (int j = 0; j < 4; ++j) acc[i][j] = 0.0f;

  for (int k0 = 0; k0 < D_; k0 += 32) {
    __syncthreads();
    // Stage A (s, bf16): 64r x 32k = 512 US4, 2 per thread.
    #pragma unroll
    for (int c = 0; c < 2; ++c) {
      int idx = c * 256 + tid;
      int k4 = idx & 7, rr = idx >> 3;
      US4 v = *reinterpret_cast<const US4*>(
          s + (size_t)(r0 + rr) * D_ + k0 + k4 * 4);
      As[rr][k4 * 4 + 0] = bf16_to_f32(v.x);
      As[rr][k4 * 4 + 1] = bf16_to_f32(v.y);
      As[rr][k4 * 4 + 2] = bf16_to_f32(v.z);
      As[rr][k4 * 4 + 3] = bf16_to_f32(v.w);
    }
    // Stage B (Wp): 64j x 32k = 512 float4, 2 per thread.
    #pragma unroll
    for (int c = 0; c < 2; ++c) {
      int idx = c * 256 + tid;
      int k4 = idx & 7, jj = idx >> 3;
      float4 v = *reinterpret_cast<const float4*>(
          Wp + (size_t)(j0 + jj) * D_ + k0 + k4 * 4);
      Bs[jj][k4 * 4 + 0] = v.x;
      Bs[jj][k4 * 4 + 1] = v.y;
      Bs[jj][k4 * 4 + 2] = v.z;
      Bs[jj][k4 * 4 + 3] = v.w;
    }
    __syncthreads();
    #pragma unroll 8
    for (int kk = 0; kk < 32; ++kk) {
      float a[4], b[4];
      #pragma unroll
      for (int i = 0; i < 4; ++i) a[i] = As[tyr * 4 + i][kk];
      #pragma unroll
      for (int j = 0; j < 4; ++j) b[j] = Bs[txj * 4 + j][kk];
      #pragma unroll
      for (int i = 0; i < 4; ++i)
        #pragma unroll
        for (int j = 0; j < 4; ++j) acc[i][j] += a[i] * b[j];
    }
  }

  float4 bv = *reinterpret_cast<const float4*>(bp + j0 + txj * 4);
  #pragma unroll
  for (int i = 0; i < 4; ++i) {
    float4 o;
    o.x = acc[i][0] + bv.x;
    o.y = acc[i][1] + bv.y;
    o.z = acc[i][2] + bv.z;
    o.w = acc[i][3] + bv.w;
    *reinterpret_cast<float4*>(
        out + (size_t)(r0 + tyr * 4 + i) * D_ + j0 + txj * 4) = o;
  }
}

extern "C" void kernel_launch(void* const* d_in, const int* in_sizes, int n_in,
                              void* d_out, int out_size, void* d_ws, size_t ws_size,
                              hipStream_t stream) {
  const float* x  = (const float*)d_in[0];   // (T,B,N,D) fp32
  const float* Wq = (const float*)d_in[1];
  const float* Wk = (const float*)d_in[2];
  const float* Wv = (const float*)d_in[3];
  const float* Wp = (const float*)d_in[4];
  const float* bp = (const float*)d_in[5];
  float* out = (float*)d_out;

  // ws: s = q*context as bf16, (T, M, D) = 64 MiB.
  unsigned short* s_ws = (unsigned short*)d_ws;

  qkv_lif_kernel<<<dim3(M_ / 16, D_ / 64), dim3(256), 0, stream>>>(
      x, Wq, Wk, Wv, s_ws);
  out_gemm_kernel<<<dim3((T_ * M_) / 64, D_ / 64), dim3(256), 0, stream>>>(
      s_ws, Wp, bp, out);
}

// Round 2
// 1088.843 us; speedup vs baseline: 2.7547x; 2.7547x over previous
//
#include <hip/hip_runtime.h>
#include <hip/hip_bf16.h>
#include <stdint.h>

// SpikingSelfAttention: out = (q*cumsum_t(k*v)) @ Wp^T + bp, q/k/v = LIF(x@W^T)
// T=4, B=16, N=1024, D=512 -> M = 16384 rows.
//
// Numerics strategy (round 2): the golden ref is fp64-compatible at every
// spike decision (round-1 fp64 pipeline gave absmax 0.0). Spikes only need
// fp64 *near* the threshold:
//   Phase 1: 2-limb bf16 MFMA GEMM (hh+hl+lh terms; err sigma ~4e-6,
//            worst-case ~2e-4) + fp32 LIF fused in registers. Flag any (m,d)
//            whose membrane ever lands within TAU=5e-4 of THR (exp. ~23K of
//            8.4M pairs) into a worklist.
//   Phase 2: recompute flagged (m,d) trajectories exactly in fp64 and
//            overwrite s. Non-flagged decisions provably match fp64.
// s = q*cumsum(k*v) is an exact small int (0..4) -> stored u8.
// Final GEMM out = s@Wp^T + bp in fp32 (needs only ~1e-3 abs accuracy).

#define T_ 4
#define M_ 16384
#define D_ 512
#define MT 64      // m rows per block
#define DT 32      // d cols per block
#define BK 32      // k per step
#define RS (BK + 8)  // LDS row stride in bf16 elems (pad 8 -> 80B, 2-way-free banks)
#define TAU 5e-4f

typedef __attribute__((ext_vector_type(8))) short bs8;   // 8 bf16 (4 VGPR)
typedef __attribute__((ext_vector_type(4))) float f32x4; // MFMA C/D

static __device__ __forceinline__ void split1(float f, ushort& h, ushort& l) {
  __hip_bfloat16 hb = __float2bfloat16(f);           // RTN hi limb
  float hf = __bfloat162float(hb);
  __hip_bfloat16 lb = __float2bfloat16(f - hf);      // RTN lo limb
  h = __builtin_bit_cast(ushort, hb);
  l = __builtin_bit_cast(ushort, lb);
}
static __device__ __forceinline__ uint32_t pack2(ushort a, ushort b) {
  return (uint32_t)a | ((uint32_t)b << 16);
}

// ---------------------------------------------------------------------------
// Phase 0: zero the worklist counter (graph-capture-safe reset each call).
// ---------------------------------------------------------------------------
__global__ void zero_count(uint32_t* c) { *c = 0; }

// ---------------------------------------------------------------------------
// Phase 1: fused 2-limb bf16-MFMA qkv GEMM + fp32 LIF + borderline flagging.
// Block 256 = 4 waves; wave w owns m-rows [w*16, w*16+16) of the 64-row tile
// for ALL 4 timesteps and 3 matrices -> per (m,d) all 12 y-values live in the
// same lane (C/D layout: col=lane&15, row=(lane>>4)*4+reg) -> LIF in-register.
// ---------------------------------------------------------------------------
__global__ __launch_bounds__(256, 2)
void qkv_mfma_lif(const float* __restrict__ x,    // (T, M, D)
                  const float* __restrict__ Wq,   // (D, D) [d][k]
                  const float* __restrict__ Wk,
                  const float* __restrict__ Wv,
                  uint8_t* __restrict__ s_out,    // (T, M, D) u8
                  uint32_t* __restrict__ count,
                  uint32_t* __restrict__ list,
                  uint32_t cap) {
  __shared__ ushort Xh[T_][MT][RS], Xl[T_][MT][RS];   // 40 KB
  __shared__ ushort Wh[3][DT][RS], Wl[3][DT][RS];     // 15 KB
  const int tid = threadIdx.x;
  const int lane = tid & 63;
  const int w = tid >> 6;              // wave id = m-quadrant
  const int d0 = blockIdx.x * DT;      // d fast in grid -> consecutive blocks
  const int m0 = blockIdx.y * MT;      //   share the x tile (L2 locality)

  f32x4 acc[T_][3][2];                 // 96 VGPR accumulator
  #pragma unroll
  for (int t = 0; t < T_; ++t)
    #pragma unroll
    for (int mat = 0; mat < 3; ++mat)
      #pragma unroll
      for (int dh = 0; dh < 2; ++dh) acc[t][mat][dh] = (f32x4)0.0f;

  for (int k0 = 0; k0 < D_; k0 += BK) {
    __syncthreads();
    // Stage X: 4t x 64m x 32k fp32 = 2048 float4 -> 8/thread; split to bf16 hi/lo.
    #pragma unroll
    for (int c = 0; c < 8; ++c) {
      int idx = c * 256 + tid;
      int k4 = idx & 7, row = idx >> 3;        // row 0..255
      int t = row >> 6, m = row & 63;
      float4 f = *reinterpret_cast<const float4*>(
          x + ((size_t)t * M_ + (size_t)(m0 + m)) * D_ + k0 + k4 * 4);
      ushort h0,h1,h2,h3,l0,l1,l2,l3;
      split1(f.x,h0,l0); split1(f.y,h1,l1); split1(f.z,h2,l2); split1(f.w,h3,l3);
      *reinterpret_cast<uint2*>(&Xh[t][m][k4*4]) = make_uint2(pack2(h0,h1), pack2(h2,h3));
      *reinterpret_cast<uint2*>(&Xl[t][m][k4*4]) = make_uint2(pack2(l0,l1), pack2(l2,l3));
    }
    // Stage W (q,k,v): 3 x 32d x 32k = 768 float4 -> 3/thread.
    #pragma unroll
    for (int c = 0; c < 3; ++c) {
      int idx = c * 256 + tid;
      int k4 = idx & 7, row = idx >> 3;        // row 0..95
      int mat = row >> 5, dd = row & 31;
      const float* wp = (mat == 0) ? Wq : ((mat == 1) ? Wk : Wv);
      float4 f = *reinterpret_cast<const float4*>(
          wp + (size_t)(d0 + dd) * D_ + k0 + k4 * 4);
      ushort h0,h1,h2,h3,l0,l1,l2,l3;
      split1(f.x,h0,l0); split1(f.y,h1,l1); split1(f.z,h2,l2); split1(f.w,h3,l3);
      *reinterpret_cast<uint2*>(&Wh[mat][dd][k4*4]) = make_uint2(pack2(h0,h1), pack2(h2,h3));
      *reinterpret_cast<uint2*>(&Wl[mat][dd][k4*4]) = make_uint2(pack2(l0,l1), pack2(l2,l3));
    }
    __syncthreads();

    // A fragments: lane -> row (lane&15) of this wave's 16 m-rows, k-slice (lane>>4)*8.
    bs8 a[T_][2];
    #pragma unroll
    for (int t = 0; t < T_; ++t) {
      a[t][0] = *reinterpret_cast<const bs8*>(&Xh[t][w*16 + (lane&15)][(lane>>4)*8]);
      a[t][1] = *reinterpret_cast<const bs8*>(&Xl[t][w*16 + (lane&15)][(lane>>4)*8]);
    }
    #pragma unroll
    for (int mat = 0; mat < 3; ++mat) {
      bs8 b[2][2];
      #pragma unroll
      for (int dh = 0; dh < 2; ++dh) {
        b[dh][0] = *reinterpret_cast<const bs8*>(&Wh[mat][dh*16 + (lane&15)][(lane>>4)*8]);
        b[dh][1] = *reinterpret_cast<const bs8*>(&Wl[mat][dh*16 + (lane&15)][(lane>>4)*8]);
      }
      #pragma unroll
      for (int t = 0; t < T_; ++t)
        #pragma unroll
        for (int dh = 0; dh < 2; ++dh) {
          acc[t][mat][dh] = __builtin_amdgcn_mfma_f32_16x16x32_bf16(
              a[t][0], b[dh][0], acc[t][mat][dh], 0, 0, 0);  // hi*hi
          acc[t][mat][dh] = __builtin_amdgcn_mfma_f32_16x16x32_bf16(
              a[t][0], b[dh][1], acc[t][mat][dh], 0, 0, 0);  // hi*lo
          acc[t][mat][dh] = __builtin_amdgcn_mfma_f32_16x16x32_bf16(
              a[t][1], b[dh][0], acc[t][mat][dh], 0, 0, 0);  // lo*hi
        }
    }
  }

  // In-register LIF. Lane holds (m = w*16 + (lane>>4)*4 + r, d = dh*16 + (lane&15)).
  const int rbase = w * 16 + ((lane >> 4) << 2);
  const int dd = lane & 15;
  #pragma unroll
  for (int dh = 0; dh < 2; ++dh) {
    const int gd = d0 + dh * 16 + dd;
    #pragma unroll
    for (int r = 0; r < 4; ++r) {
      const int gm = m0 + rbase + r;
      float mq = 0.f, mk = 0.f, mv = 0.f;
      int ctx = 0; bool flag = false;
      #pragma unroll
      for (int t = 0; t < T_; ++t) {
        mq = mq * 0.9f + acc[t][0][dh][r];
        mk = mk * 0.9f + acc[t][1][dh][r];
        mv = mv * 0.9f + acc[t][2][dh][r];
        flag |= (fabsf(mq - 1.f) < TAU) || (fabsf(mk - 1.f) < TAU) ||
                (fabsf(mv - 1.f) < TAU);
        int sq = (mq >= 1.f); int sk = (mk >= 1.f); int sv = (mv >= 1.f);
        mq -= (float)sq; mk -= (float)sk; mv -= (float)sv;
        ctx += sk & sv;
        s_out[(size_t)t * (M_ * (size_t)D_) + (size_t)gm * D_ + gd] =
            (uint8_t)(sq ? ctx : 0);
      }
      if (flag) {
        uint32_t pos = atomicAdd(count, 1u);
        if (pos < cap) list[pos] = ((uint32_t)gm << 9) | (uint32_t)gd;
      }
    }
  }
}

// ---------------------------------------------------------------------------
// Phase 2: exact fp64 recompute of flagged (m,d) trajectories. 1 wave/entry,
// lanes split K (8 k each), butterfly all-reduce, fp64 LIF, overwrite s.
// ---------------------------------------------------------------------------
__global__ __launch_bounds__(64, 8)
void fix_borderline(const float* __restrict__ x,
                    const float* __restrict__ Wq,
                    const float* __restrict__ Wk,
                    const float* __restrict__ Wv,
                    uint8_t* __restrict__ s_out,
                    const uint32_t* __restrict__ count,
                    const uint32_t* __restrict__ list,
                    uint32_t cap) {
  uint32_t n = *count; if (n > cap) n = cap;
  const int lane = threadIdx.x;
  for (uint32_t j = blockIdx.x; j < n; j += gridDim.x) {
    uint32_t e = list[j];
    int m = (int)(e >> 9), d = (int)(e & 511);
    const int kb = lane * 8;
    float xr[T_][8], wr[3][8];
    #pragma unroll
    for (int t = 0; t < T_; ++t) {
      float4 a = *reinterpret_cast<const float4*>(x + ((size_t)t*M_ + m)*D_ + kb);
      float4 b = *reinterpret_cast<const float4*>(x + ((size_t)t*M_ + m)*D_ + kb + 4);
      xr[t][0]=a.x; xr[t][1]=a.y; xr[t][2]=a.z; xr[t][3]=a.w;
      xr[t][4]=b.x; xr[t][5]=b.y; xr[t][6]=b.z; xr[t][7]=b.w;
    }
    #pragma unroll
    for (int mat = 0; mat < 3; ++mat) {
      const float* wp = (mat == 0) ? Wq : ((mat == 1) ? Wk : Wv);
      float4 a = *reinterpret_cast<const float4*>(wp + (size_t)d*D_ + kb);
      float4 b = *reinterpret_cast<const float4*>(wp + (size_t)d*D_ + kb + 4);
      wr[mat][0]=a.x; wr[mat][1]=a.y; wr[mat][2]=a.z; wr[mat][3]=a.w;
      wr[mat][4]=b.x; wr[mat][5]=b.y; wr[mat][6]=b.z; wr[mat][7]=b.w;
    }
    double pd[T_][3];
    #pragma unroll
    for (int t = 0; t < T_; ++t)
      #pragma unroll
      for (int mat = 0; mat < 3; ++mat) {
        double s = 0.0;
        #pragma unroll
        for (int i = 0; i < 8; ++i) s += (double)xr[t][i] * (double)wr[mat][i];
        pd[t][mat] = s;
      }
    #pragma unroll
    for (int off = 32; off > 0; off >>= 1)
      #pragma unroll
      for (int t = 0; t < T_; ++t)
        #pragma unroll
        for (int mat = 0; mat < 3; ++mat)
          pd[t][mat] += __shfl_xor(pd[t][mat], off);
    // Exact fp64 LIF (all lanes redundantly).
    double mq = 0.0, mk = 0.0, mv = 0.0;
    int ctx = 0; uint8_t sv4[T_];
    #pragma unroll
    for (int t = 0; t < T_; ++t) {
      mq = mq * 0.9 + pd[t][0];
      mk = mk * 0.9 + pd[t][1];
      mv = mv * 0.9 + pd[t][2];
      int sq = (mq >= 1.0); int sk = (mk >= 1.0); int sv = (mv >= 1.0);
      mq -= (double)sq; mk -= (double)sk; mv -= (double)sv;
      ctx += sk & sv;
      sv4[t] = (uint8_t)(sq ? ctx : 0);
    }
    if (lane < T_)
      s_out[(size_t)lane * (M_ * (size_t)D_) + (size_t)m * D_ + d] = sv4[lane];
  }
}

// ---------------------------------------------------------------------------
// Phase 3: out = s @ Wp^T + bp  (R = 65536 rows, K = 512). fp32 vector FMA.
// ---------------------------------------------------------------------------
__global__ __launch_bounds__(256, 2)
void out_gemm_kernel(const uint8_t* __restrict__ s,   // (R, D) u8
                     const float* __restrict__ Wp,    // (D, D) [j][d]
                     const float* __restrict__ bp,
                     float* __restrict__ out) {       // (R, D)
  __shared__ float As[64][33];
  __shared__ float Bs[64][33];
  const int tid = threadIdx.x;
  const int txj = tid & 15;
  const int tyr = tid >> 4;
  const int r0 = blockIdx.x * 64;
  const int j0 = blockIdx.y * 64;

  float acc[4][4];
  #pragma unroll
  for (int i = 0; i < 4; ++i)
    #pragma unroll
    for (int j = 0; j < 4; ++j) acc[i][j] = 0.0f;

  for (int k0 = 0; k0 < D_; k0 += 32) {
    __syncthreads();
    // Stage A (s, u8): 64r x 32k = 512 uchar4 -> 2/thread.
    #pragma unroll
    for (int c = 0; c < 2; ++c) {
      int idx = c * 256 + tid;
      int k4 = idx & 7, rr = idx >> 3;
      uchar4 v = *reinterpret_cast<const uchar4*>(
          s + (size_t)(r0 + rr) * D_ + k0 + k4 * 4);
      As[rr][k4*4+0] = (float)v.x;
      As[rr][k4*4+1] = (float)v.y;
      As[rr][k4*4+2] = (float)v.z;
      As[rr][k4*4+3] = (float)v.w;
    }
    // Stage B (Wp): 64j x 32k = 512 float4 -> 2/thread.
    #pragma unroll
    for (int c = 0; c < 2; ++c) {
      int idx = c * 256 + tid;
      int k4 = idx & 7, jj = idx >> 3;
      float4 v = *reinterpret_cast<const float4*>(
          Wp + (size_t)(j0 + jj) * D_ + k0 + k4 * 4);
      Bs[jj][k4*4+0] = v.x; Bs[jj][k4*4+1] = v.y;
      Bs[jj][k4*4+2] = v.z; Bs[jj][k4*4+3] = v.w;
    }
    __syncthreads();
    #pragma unroll 8
    for (int kk = 0; kk < 32; ++kk) {
      float a[4], b[4];
      #pragma unroll
      for (int i = 0; i < 4; ++i) a[i] = As[tyr*4+i][kk];
      #pragma unroll
      for (int j = 0; j < 4; ++j) b[j] = Bs[txj*4+j][kk];
      #pragma unroll
      for (int i = 0; i < 4; ++i)
        #pragma unroll
        for (int j = 0; j < 4; ++j) acc[i][j] += a[i] * b[j];
    }
  }

  float4 bv = *reinterpret_cast<const float4*>(bp + j0 + txj * 4);
  #pragma unroll
  for (int i = 0; i < 4; ++i) {
    float4 o;
    o.x = acc[i][0] + bv.x; o.y = acc[i][1] + bv.y;
    o.z = acc[i][2] + bv.z; o.w = acc[i][3] + bv.w;
    *reinterpret_cast<float4*>(
        out + (size_t)(r0 + tyr*4 + i) * D_ + j0 + txj*4) = o;
  }
}

extern "C" void kernel_launch(void* const* d_in, const int* in_sizes, int n_in,
                              void* d_out, int out_size, void* d_ws, size_t ws_size,
                              hipStream_t stream) {
  const float* x  = (const float*)d_in[0];
  const float* Wq = (const float*)d_in[1];
  const float* Wk = (const float*)d_in[2];
  const float* Wv = (const float*)d_in[3];
  const float* Wp = (const float*)d_in[4];
  const float* bp = (const float*)d_in[5];
  float* out = (float*)d_out;

  // ws layout: s u8 (32 MB) | count u32 (16B-aligned slot) | worklist u32[].
  const size_t s_bytes = (size_t)T_ * M_ * D_;           // 32 MiB
  uint8_t*  s_ws  = (uint8_t*)d_ws;
  uint32_t* count = (uint32_t*)((char*)d_ws + s_bytes);
  uint32_t* list  = (uint32_t*)((char*)d_ws + s_bytes + 16);
  uint32_t cap = 0;
  if (ws_size > s_bytes + 16)
    cap = (uint32_t)((ws_size - s_bytes - 16) / sizeof(uint32_t));

  zero_count<<<1, 1, 0, stream>>>(count);
  qkv_mfma_lif<<<dim3(D_/DT, M_/MT), dim3(256), 0, stream>>>(
      x, Wq, Wk, Wv, s_ws, count, list, cap);
  fix_borderline<<<dim3(4096), dim3(64), 0, stream>>>(
      x, Wq, Wk, Wv, s_ws, count, list, cap);
  out_gemm_kernel<<<dim3((T_*M_)/64, D_/64), dim3(256), 0, stream>>>(
      s_ws, Wp, bp, out);
}

// Round 3
// 577.133 us; speedup vs baseline: 5.1971x; 1.8866x over previous
//
#include <hip/hip_runtime.h>
#include <hip/hip_bf16.h>
#include <stdint.h>

// SpikingSelfAttention: out = (q*cumsum_t(k*v)) @ Wp^T + bp, q/k/v = LIF(x@W^T)
// T=4, B=16, N=1024, D=512 -> M = 16384 rows.
//
// Phase 1: 2-limb bf16 MFMA qkv GEMM (hh+hl+lh) + fp32 LIF in registers;
//          flag |mem-THR| < TAU into a worklist.
// Phase 2: exact fp64 recompute of flagged (m,d) trajectories (tiny).
// Phase 3: out = s @ Wp^T + bp as a 1-limb bf16 MFMA GEMM (s in {0..4} is
//          exact bf16; Wp bf16 rounding gives ~4e-3 worst abs err vs 2.2e-2
//          threshold). Wp pre-converted to bf16 once.

#define T_ 4
#define M_ 16384
#define D_ 512
#define MT 64
#define DT 32
#define BK 32
#define RS (BK + 8)
#define TAU 5e-4f

typedef __attribute__((ext_vector_type(8))) short bs8;   // 8 bf16 (4 VGPR)
typedef __attribute__((ext_vector_type(4))) float f32x4; // MFMA C/D
typedef unsigned short u16;

static __device__ __forceinline__ void split1(float f, u16& h, u16& l) {
  __hip_bfloat16 hb = __float2bfloat16(f);           // RTN hi limb
  float hf = __bfloat162float(hb);
  __hip_bfloat16 lb = __float2bfloat16(f - hf);      // RTN lo limb
  h = __builtin_bit_cast(u16, hb);
  l = __builtin_bit_cast(u16, lb);
}
static __device__ __forceinline__ uint32_t pack2(u16 a, u16 b) {
  return (uint32_t)a | ((uint32_t)b << 16);
}
// pack two exact-int floats as bf16 pair (no rounding needed)
static __device__ __forceinline__ uint32_t packf2(float a, float b) {
  return (__builtin_bit_cast(uint32_t, a) >> 16) |
         (__builtin_bit_cast(uint32_t, b) & 0xFFFF0000u);
}

// ---------------------------------------------------------------------------
__global__ void zero_count(uint32_t* c) { *c = 0; }

// One-time Wp fp32 -> bf16 (RTN). 262144 elems, 8/thread.
__global__ void conv_wp(const float* __restrict__ Wp, u16* __restrict__ wpb) {
  int i = (blockIdx.x * 256 + threadIdx.x) * 8;
  float4 a = *reinterpret_cast<const float4*>(Wp + i);
  float4 b = *reinterpret_cast<const float4*>(Wp + i + 4);
  u16 h[8];
  h[0] = __builtin_bit_cast(u16, __float2bfloat16(a.x));
  h[1] = __builtin_bit_cast(u16, __float2bfloat16(a.y));
  h[2] = __builtin_bit_cast(u16, __float2bfloat16(a.z));
  h[3] = __builtin_bit_cast(u16, __float2bfloat16(a.w));
  h[4] = __builtin_bit_cast(u16, __float2bfloat16(b.x));
  h[5] = __builtin_bit_cast(u16, __float2bfloat16(b.y));
  h[6] = __builtin_bit_cast(u16, __float2bfloat16(b.z));
  h[7] = __builtin_bit_cast(u16, __float2bfloat16(b.w));
  uint4 o;
  o.x = pack2(h[0], h[1]); o.y = pack2(h[2], h[3]);
  o.z = pack2(h[4], h[5]); o.w = pack2(h[6], h[7]);
  *reinterpret_cast<uint4*>(wpb + i) = o;
}

// ---------------------------------------------------------------------------
// Phase 1 (unchanged from round 2, proven): fused 2-limb bf16-MFMA qkv GEMM +
// fp32 LIF + borderline flagging.
// ---------------------------------------------------------------------------
__global__ __launch_bounds__(256, 2)
void qkv_mfma_lif(const float* __restrict__ x,
                  const float* __restrict__ Wq,
                  const float* __restrict__ Wk,
                  const float* __restrict__ Wv,
                  uint8_t* __restrict__ s_out,
                  uint32_t* __restrict__ count,
                  uint32_t* __restrict__ list,
                  uint32_t cap) {
  __shared__ u16 Xh[T_][MT][RS], Xl[T_][MT][RS];
  __shared__ u16 Wh[3][DT][RS], Wl[3][DT][RS];
  const int tid = threadIdx.x;
  const int lane = tid & 63;
  const int w = tid >> 6;
  const int d0 = blockIdx.x * DT;
  const int m0 = blockIdx.y * MT;

  f32x4 acc[T_][3][2];
  #pragma unroll
  for (int t = 0; t < T_; ++t)
    #pragma unroll
    for (int mat = 0; mat < 3; ++mat)
      #pragma unroll
      for (int dh = 0; dh < 2; ++dh) acc[t][mat][dh] = (f32x4)0.0f;

  for (int k0 = 0; k0 < D_; k0 += BK) {
    __syncthreads();
    #pragma unroll
    for (int c = 0; c < 8; ++c) {
      int idx = c * 256 + tid;
      int k4 = idx & 7, row = idx >> 3;
      int t = row >> 6, m = row & 63;
      float4 f = *reinterpret_cast<const float4*>(
          x + ((size_t)t * M_ + (size_t)(m0 + m)) * D_ + k0 + k4 * 4);
      u16 h0,h1,h2,h3,l0,l1,l2,l3;
      split1(f.x,h0,l0); split1(f.y,h1,l1); split1(f.z,h2,l2); split1(f.w,h3,l3);
      *reinterpret_cast<uint2*>(&Xh[t][m][k4*4]) = make_uint2(pack2(h0,h1), pack2(h2,h3));
      *reinterpret_cast<uint2*>(&Xl[t][m][k4*4]) = make_uint2(pack2(l0,l1), pack2(l2,l3));
    }
    #pragma unroll
    for (int c = 0; c < 3; ++c) {
      int idx = c * 256 + tid;
      int k4 = idx & 7, row = idx >> 3;
      int mat = row >> 5, dd = row & 31;
      const float* wp = (mat == 0) ? Wq : ((mat == 1) ? Wk : Wv);
      float4 f = *reinterpret_cast<const float4*>(
          wp + (size_t)(d0 + dd) * D_ + k0 + k4 * 4);
      u16 h0,h1,h2,h3,l0,l1,l2,l3;
      split1(f.x,h0,l0); split1(f.y,h1,l1); split1(f.z,h2,l2); split1(f.w,h3,l3);
      *reinterpret_cast<uint2*>(&Wh[mat][dd][k4*4]) = make_uint2(pack2(h0,h1), pack2(h2,h3));
      *reinterpret_cast<uint2*>(&Wl[mat][dd][k4*4]) = make_uint2(pack2(l0,l1), pack2(l2,l3));
    }
    __syncthreads();

    bs8 a[T_][2];
    #pragma unroll
    for (int t = 0; t < T_; ++t) {
      a[t][0] = *reinterpret_cast<const bs8*>(&Xh[t][w*16 + (lane&15)][(lane>>4)*8]);
      a[t][1] = *reinterpret_cast<const bs8*>(&Xl[t][w*16 + (lane&15)][(lane>>4)*8]);
    }
    #pragma unroll
    for (int mat = 0; mat < 3; ++mat) {
      bs8 b[2][2];
      #pragma unroll
      for (int dh = 0; dh < 2; ++dh) {
        b[dh][0] = *reinterpret_cast<const bs8*>(&Wh[mat][dh*16 + (lane&15)][(lane>>4)*8]);
        b[dh][1] = *reinterpret_cast<const bs8*>(&Wl[mat][dh*16 + (lane&15)][(lane>>4)*8]);
      }
      #pragma unroll
      for (int t = 0; t < T_; ++t)
        #pragma unroll
        for (int dh = 0; dh < 2; ++dh) {
          acc[t][mat][dh] = __builtin_amdgcn_mfma_f32_16x16x32_bf16(
              a[t][0], b[dh][0], acc[t][mat][dh], 0, 0, 0);
          acc[t][mat][dh] = __builtin_amdgcn_mfma_f32_16x16x32_bf16(
              a[t][0], b[dh][1], acc[t][mat][dh], 0, 0, 0);
          acc[t][mat][dh] = __builtin_amdgcn_mfma_f32_16x16x32_bf16(
              a[t][1], b[dh][0], acc[t][mat][dh], 0, 0, 0);
        }
    }
  }

  const int rbase = w * 16 + ((lane >> 4) << 2);
  const int dd = lane & 15;
  #pragma unroll
  for (int dh = 0; dh < 2; ++dh) {
    const int gd = d0 + dh * 16 + dd;
    #pragma unroll
    for (int r = 0; r < 4; ++r) {
      const int gm = m0 + rbase + r;
      float mq = 0.f, mk = 0.f, mv = 0.f;
      int ctx = 0; bool flag = false;
      #pragma unroll
      for (int t = 0; t < T_; ++t) {
        mq = mq * 0.9f + acc[t][0][dh][r];
        mk = mk * 0.9f + acc[t][1][dh][r];
        mv = mv * 0.9f + acc[t][2][dh][r];
        flag |= (fabsf(mq - 1.f) < TAU) || (fabsf(mk - 1.f) < TAU) ||
                (fabsf(mv - 1.f) < TAU);
        int sq = (mq >= 1.f); int sk = (mk >= 1.f); int sv = (mv >= 1.f);
        mq -= (float)sq; mk -= (float)sk; mv -= (float)sv;
        ctx += sk & sv;
        s_out[(size_t)t * (M_ * (size_t)D_) + (size_t)gm * D_ + gd] =
            (uint8_t)(sq ? ctx : 0);
      }
      if (flag) {
        uint32_t pos = atomicAdd(count, 1u);
        if (pos < cap) list[pos] = ((uint32_t)gm << 9) | (uint32_t)gd;
      }
    }
  }
}

// ---------------------------------------------------------------------------
// Phase 2 (unchanged): exact fp64 recompute of flagged trajectories.
// ---------------------------------------------------------------------------
__global__ __launch_bounds__(64, 8)
void fix_borderline(const float* __restrict__ x,
                    const float* __restrict__ Wq,
                    const float* __restrict__ Wk,
                    const float* __restrict__ Wv,
                    uint8_t* __restrict__ s_out,
                    const uint32_t* __restrict__ count,
                    const uint32_t* __restrict__ list,
                    uint32_t cap) {
  uint32_t n = *count; if (n > cap) n = cap;
  const int lane = threadIdx.x;
  for (uint32_t j = blockIdx.x; j < n; j += gridDim.x) {
    uint32_t e = list[j];
    int m = (int)(e >> 9), d = (int)(e & 511);
    const int kb = lane * 8;
    float xr[T_][8], wr[3][8];
    #pragma unroll
    for (int t = 0; t < T_; ++t) {
      float4 a = *reinterpret_cast<const float4*>(x + ((size_t)t*M_ + m)*D_ + kb);
      float4 b = *reinterpret_cast<const float4*>(x + ((size_t)t*M_ + m)*D_ + kb + 4);
      xr[t][0]=a.x; xr[t][1]=a.y; xr[t][2]=a.z; xr[t][3]=a.w;
      xr[t][4]=b.x; xr[t][5]=b.y; xr[t][6]=b.z; xr[t][7]=b.w;
    }
    #pragma unroll
    for (int mat = 0; mat < 3; ++mat) {
      const float* wp = (mat == 0) ? Wq : ((mat == 1) ? Wk : Wv);
      float4 a = *reinterpret_cast<const float4*>(wp + (size_t)d*D_ + kb);
      float4 b = *reinterpret_cast<const float4*>(wp + (size_t)d*D_ + kb + 4);
      wr[mat][0]=a.x; wr[mat][1]=a.y; wr[mat][2]=a.z; wr[mat][3]=a.w;
      wr[mat][4]=b.x; wr[mat][5]=b.y; wr[mat][6]=b.z; wr[mat][7]=b.w;
    }
    double pd[T_][3];
    #pragma unroll
    for (int t = 0; t < T_; ++t)
      #pragma unroll
      for (int mat = 0; mat < 3; ++mat) {
        double s = 0.0;
        #pragma unroll
        for (int i = 0; i < 8; ++i) s += (double)xr[t][i] * (double)wr[mat][i];
        pd[t][mat] = s;
      }
    #pragma unroll
    for (int off = 32; off > 0; off >>= 1)
      #pragma unroll
      for (int t = 0; t < T_; ++t)
        #pragma unroll
        for (int mat = 0; mat < 3; ++mat)
          pd[t][mat] += __shfl_xor(pd[t][mat], off);
    double mq = 0.0, mk = 0.0, mv = 0.0;
    int ctx = 0; uint8_t sv4[T_];
    #pragma unroll
    for (int t = 0; t < T_; ++t) {
      mq = mq * 0.9 + pd[t][0];
      mk = mk * 0.9 + pd[t][1];
      mv = mv * 0.9 + pd[t][2];
      int sq = (mq >= 1.0); int sk = (mk >= 1.0); int sv = (mv >= 1.0);
      mq -= (double)sq; mk -= (double)sk; mv -= (double)sv;
      ctx += sk & sv;
      sv4[t] = (uint8_t)(sq ? ctx : 0);
    }
    if (lane < T_)
      s_out[(size_t)lane * (M_ * (size_t)D_) + (size_t)m * D_ + d] = sv4[lane];
  }
}

// ---------------------------------------------------------------------------
// Phase 3 (NEW): out = s @ Wp^T + bp via bf16 MFMA.
// Block 256 = 4 waves; tile 128 rows x 64 cols; wave w owns rows
// [w*32, w*32+32) as 2 row-groups of 16. Fragment scheme identical to the
// proven qkv kernel (A row-major k-consecutive, B row-major k-consecutive,
// C/D col=lane&15, row=(lane>>4)*4+reg).
// ---------------------------------------------------------------------------
__global__ __launch_bounds__(256, 4)
void out_gemm_mfma(const uint8_t* __restrict__ s,   // (65536, 512) u8
                   const u16* __restrict__ wpb,     // (512, 512) bf16 [j][k]
                   const float* __restrict__ bp,
                   float* __restrict__ out) {       // (65536, 512) f32
  __shared__ u16 As[128][BK];  // 8 KB, linear (frag reads are permuted-1KB)
  __shared__ u16 Bs[64][BK];   // 4 KB
  const int tid = threadIdx.x;
  const int lane = tid & 63;
  const int w = tid >> 6;
  const int j0 = blockIdx.x * 64;
  const int r0 = blockIdx.y * 128;

  f32x4 acc[2][4];
  #pragma unroll
  for (int rg = 0; rg < 2; ++rg)
    #pragma unroll
    for (int jf = 0; jf < 4; ++jf) acc[rg][jf] = (f32x4)0.0f;

  for (int k0 = 0; k0 < D_; k0 += BK) {
    __syncthreads();
    // Stage A: 128 rows x 32 k of u8 -> bf16. 16 u8 per thread.
    {
      int row = tid >> 1, half = tid & 1;
      uint4 u = *reinterpret_cast<const uint4*>(
          s + (size_t)(r0 + row) * D_ + k0 + half * 16);
      uint32_t dw[4] = {u.x, u.y, u.z, u.w};
      uint32_t pk[8];
      #pragma unroll
      for (int q = 0; q < 4; ++q) {
        uint32_t v = dw[q];
        float f0 = (float)(v & 0xff);
        float f1 = (float)((v >> 8) & 0xff);
        float f2 = (float)((v >> 16) & 0xff);
        float f3 = (float)(v >> 24);
        pk[q*2+0] = packf2(f0, f1);
        pk[q*2+1] = packf2(f2, f3);
      }
      uint4* dst = reinterpret_cast<uint4*>(&As[row][half * 16]);
      dst[0] = make_uint4(pk[0], pk[1], pk[2], pk[3]);
      dst[1] = make_uint4(pk[4], pk[5], pk[6], pk[7]);
    }
    // Stage B: 64 rows x 32 k bf16 copy. 16 B per thread.
    {
      int row = tid >> 2, q = tid & 3;
      uint4 u = *reinterpret_cast<const uint4*>(
          wpb + (size_t)(j0 + row) * D_ + k0 + q * 8);
      *reinterpret_cast<uint4*>(&Bs[row][q * 8]) = u;
    }
    __syncthreads();

    const int rb = w * 32;
    bs8 a0 = *reinterpret_cast<const bs8*>(&As[rb      + (lane&15)][(lane>>4)*8]);
    bs8 a1 = *reinterpret_cast<const bs8*>(&As[rb + 16 + (lane&15)][(lane>>4)*8]);
    #pragma unroll
    for (int jf = 0; jf < 4; ++jf) {
      bs8 b = *reinterpret_cast<const bs8*>(&Bs[jf*16 + (lane&15)][(lane>>4)*8]);
      acc[0][jf] = __builtin_amdgcn_mfma_f32_16x16x32_bf16(a0, b, acc[0][jf], 0, 0, 0);
      acc[1][jf] = __builtin_amdgcn_mfma_f32_16x16x32_bf16(a1, b, acc[1][jf], 0, 0, 0);
    }
  }

  const int col = lane & 15;
  const int rloc = (lane >> 4) * 4;
  #pragma unroll
  for (int jf = 0; jf < 4; ++jf) {
    float bv = bp[j0 + jf * 16 + col];
    #pragma unroll
    for (int rg = 0; rg < 2; ++rg) {
      #pragma unroll
      for (int reg = 0; reg < 4; ++reg) {
        out[(size_t)(r0 + w * 32 + rg * 16 + rloc + reg) * D_ +
            j0 + jf * 16 + col] = acc[rg][jf][reg] + bv;
      }
    }
  }
}

extern "C" void kernel_launch(void* const* d_in, const int* in_sizes, int n_in,
                              void* d_out, int out_size, void* d_ws, size_t ws_size,
                              hipStream_t stream) {
  const float* x  = (const float*)d_in[0];
  const float* Wq = (const float*)d_in[1];
  const float* Wk = (const float*)d_in[2];
  const float* Wv = (const float*)d_in[3];
  const float* Wp = (const float*)d_in[4];
  const float* bp = (const float*)d_in[5];
  float* out = (float*)d_out;

  // ws layout: s u8 (32 MB) | wp bf16 (512 KB) | count (64 B) | list u32[].
  // (round 1 proved ws_size >= 64 MB: it held a 64 MB buffer.)
  const size_t s_bytes  = (size_t)T_ * M_ * D_;        // 32 MiB
  const size_t wp_bytes = (size_t)D_ * D_ * sizeof(u16);
  uint8_t*  s_ws  = (uint8_t*)d_ws;
  u16*      wpb   = (u16*)((char*)d_ws + s_bytes);
  uint32_t* count = (uint32_t*)((char*)d_ws + s_bytes + wp_bytes);
  uint32_t* list  = (uint32_t*)((char*)d_ws + s_bytes + wp_bytes + 64);
  uint32_t cap = 0;
  const size_t head = s_bytes + wp_bytes + 64;
  if (ws_size > head) cap = (uint32_t)((ws_size - head) / sizeof(uint32_t));

  zero_count<<<1, 1, 0, stream>>>(count);
  conv_wp<<<dim3(128), dim3(256), 0, stream>>>(Wp, wpb);
  qkv_mfma_lif<<<dim3(D_/DT, M_/MT), dim3(256), 0, stream>>>(
      x, Wq, Wk, Wv, s_ws, count, list, cap);
  fix_borderline<<<dim3(4096), dim3(64), 0, stream>>>(
      x, Wq, Wk, Wv, s_ws, count, list, cap);
  out_gemm_mfma<<<dim3(D_/64, (T_*M_)/128), dim3(256), 0, stream>>>(
      s_ws, wpb, bp, out);
}